// Round 1
// baseline (15.854 us; speedup 1.0000x reference)
//
#include <hip/hip_runtime.h>
#include <math.h>

// LorentzRankingLoss: K anchors gathered from voxel_emb [D=32, S=H*W*Z] (B=1),
// compared against label_emb [C=105, D=32] rows. One thread per anchor.
//
// d_pos = acosh(max(xt*yt - x.y, 1+1e-7)); triplet = max(0.1 + d_pos - d_neg, 0)
// out = mean over anchors of mean over 8 negatives.

#define NUM_NEG 8

// Compute lorentz distance between register-resident x[32] (with precomputed
// xt = sqrt(1+|x|^2)) and a 128B-aligned label row (float4 loads).
__device__ __forceinline__ float lorentz_dist_row(const float x[32], float xt,
                                                  const float* __restrict__ yrow) {
    float yy = 0.f, dot = 0.f;
#pragma unroll
    for (int q = 0; q < 8; ++q) {
        float4 y4 = reinterpret_cast<const float4*>(yrow)[q];
        yy  = fmaf(y4.x, y4.x, yy);
        yy  = fmaf(y4.y, y4.y, yy);
        yy  = fmaf(y4.z, y4.z, yy);
        yy  = fmaf(y4.w, y4.w, yy);
        dot = fmaf(y4.x, x[q * 4 + 0], dot);
        dot = fmaf(y4.y, x[q * 4 + 1], dot);
        dot = fmaf(y4.z, x[q * 4 + 2], dot);
        dot = fmaf(y4.w, x[q * 4 + 3], dot);
    }
    float yt  = sqrtf(1.0f + yy);
    float arg = fmaxf(fmaf(xt, yt, -dot), 1.0f + 1e-7f);
    return acoshf(arg);
}

__global__ __launch_bounds__(64)
void lorentz_partial_kernel(const float* __restrict__ voxel,   // [32][S]
                            const float* __restrict__ label,   // [C][32]
                            const int* __restrict__ sidx,      // [K]
                            const int* __restrict__ scls,      // [K]
                            const int* __restrict__ negc,      // [K][8]
                            float* __restrict__ partial,       // [gridDim.x]
                            int K, int S) {
    int a = blockIdx.x * 64 + threadIdx.x;
    float acc = 0.f;
    if (a < K) {
        int idx = sidx[a];
        float x[32];
        // 32 independent scattered loads (stride S floats between planes).
#pragma unroll
        for (int d = 0; d < 32; ++d)
            x[d] = voxel[(size_t)d * (size_t)S + (size_t)idx];

        float xx = 0.f;
#pragma unroll
        for (int d = 0; d < 32; ++d) xx = fmaf(x[d], x[d], xx);
        float xt = sqrtf(1.0f + xx);

        int pc = scls[a];
        float dpos = lorentz_dist_row(x, xt, label + (size_t)pc * 32);

        float sum = 0.f;
#pragma unroll
        for (int m = 0; m < NUM_NEG; ++m) {
            int nc = negc[a * NUM_NEG + m];
            float dneg = lorentz_dist_row(x, xt, label + (size_t)nc * 32);
            sum += fmaxf(0.1f + dpos - dneg, 0.f);
        }
        acc = sum * (1.0f / (float)NUM_NEG);
    }
    // full-wave (64-lane) butterfly reduce
#pragma unroll
    for (int o = 32; o > 0; o >>= 1) acc += __shfl_down(acc, o);
    if (threadIdx.x == 0) partial[blockIdx.x] = acc;
}

__global__ __launch_bounds__(64)
void lorentz_reduce_kernel(const float* __restrict__ partial, int nb,
                           float* __restrict__ out, float inv_k) {
    float s = 0.f;
    for (int i = threadIdx.x; i < nb; i += 64) s += partial[i];
#pragma unroll
    for (int o = 32; o > 0; o >>= 1) s += __shfl_down(s, o);
    if (threadIdx.x == 0) out[0] = s * inv_k;
}

extern "C" void kernel_launch(void* const* d_in, const int* in_sizes, int n_in,
                              void* d_out, int out_size, void* d_ws, size_t ws_size,
                              hipStream_t stream) {
    const float* voxel = (const float*)d_in[0];   // [B,D,H,W,Z] = [1,32,S]
    // d_in[1] = labels [B,H,W,Z] -- unused in the computation
    const float* label = (const float*)d_in[2];   // [105,32]
    const int* sidx    = (const int*)d_in[3];     // [K]
    const int* scls    = (const int*)d_in[4];     // [K]
    const int* negc    = (const int*)d_in[5];     // [K,8]

    int K = in_sizes[3];
    int S = in_sizes[1];                          // B*H*W*Z spatial count (B=1)

    float* partial = (float*)d_ws;
    float* out     = (float*)d_out;

    int nb = (K + 63) / 64;
    lorentz_partial_kernel<<<nb, 64, 0, stream>>>(voxel, label, sidx, scls, negc,
                                                  partial, K, S);
    lorentz_reduce_kernel<<<1, 64, 0, stream>>>(partial, nb, out, 1.0f / (float)K);
}

// Round 2
// 12.284 us; speedup vs baseline: 1.2907x; 1.2907x over previous
//
#include <hip/hip_runtime.h>
#include <math.h>

// LorentzRankingLoss: K anchors gathered from voxel_emb [D=32, S=H*W*Z] (B=1),
// label_emb [C=105, D=32]. One thread per (anchor, negative) pair:
// K*8 threads -> 840 waves (8x the latency-hiding of one-thread-per-anchor).
// The 8 sibling lanes of an anchor issue identical gather addresses, which
// the coalescer merges -> no extra HBM traffic, only replicated VALU.

#define NUM_NEG 8

__device__ __forceinline__ float lorentz_dist_row(const float x[32], float xt,
                                                  const float* __restrict__ yrow) {
    float yy = 0.f, dot = 0.f;
#pragma unroll
    for (int q = 0; q < 8; ++q) {
        float4 y4 = reinterpret_cast<const float4*>(yrow)[q];
        yy  = fmaf(y4.x, y4.x, yy);
        yy  = fmaf(y4.y, y4.y, yy);
        yy  = fmaf(y4.z, y4.z, yy);
        yy  = fmaf(y4.w, y4.w, yy);
        dot = fmaf(y4.x, x[q * 4 + 0], dot);
        dot = fmaf(y4.y, x[q * 4 + 1], dot);
        dot = fmaf(y4.z, x[q * 4 + 2], dot);
        dot = fmaf(y4.w, x[q * 4 + 3], dot);
    }
    float yt  = sqrtf(1.0f + yy);
    float arg = fmaxf(fmaf(xt, yt, -dot), 1.0f + 1e-7f);
    return acoshf(arg);
}

__global__ __launch_bounds__(256)
void lorentz_pair_kernel(const float* __restrict__ voxel,   // [32][S]
                         const float* __restrict__ label,   // [C][32]
                         const int* __restrict__ sidx,      // [K]
                         const int* __restrict__ scls,      // [K]
                         const int* __restrict__ negc,      // [K][8]
                         float* __restrict__ partial,       // [gridDim.x]
                         int K, int S) {
    int t = blockIdx.x * 256 + threadIdx.x;
    float tri = 0.f;
    if (t < K * NUM_NEG) {
        int a = t >> 3;               // anchor
        int idx = sidx[a];            // 8 sibling lanes: same address (merged)
        float x[32];
#pragma unroll
        for (int d = 0; d < 32; ++d)
            x[d] = voxel[(size_t)d * (size_t)S + (size_t)idx];

        float xx = 0.f;
#pragma unroll
        for (int d = 0; d < 32; ++d) xx = fmaf(x[d], x[d], xx);
        float xt = sqrtf(1.0f + xx);

        float dpos = lorentz_dist_row(x, xt, label + (size_t)scls[a] * 32);
        float dneg = lorentz_dist_row(x, xt, label + (size_t)negc[t] * 32);
        tri = fmaxf(0.1f + dpos - dneg, 0.f);
    }

    // wave reduce (64 lanes)
#pragma unroll
    for (int o = 32; o > 0; o >>= 1) tri += __shfl_down(tri, o);

    __shared__ float ws[4];
    int lane = threadIdx.x & 63, w = threadIdx.x >> 6;
    if (lane == 0) ws[w] = tri;
    __syncthreads();
    if (threadIdx.x == 0)
        partial[blockIdx.x] = ws[0] + ws[1] + ws[2] + ws[3];
}

__global__ __launch_bounds__(64)
void lorentz_reduce_kernel(const float* __restrict__ partial, int nb,
                           float* __restrict__ out, float scale) {
    float s = 0.f;
    for (int i = threadIdx.x; i < nb; i += 64) s += partial[i];
#pragma unroll
    for (int o = 32; o > 0; o >>= 1) s += __shfl_down(s, o);
    if (threadIdx.x == 0) out[0] = s * scale;
}

extern "C" void kernel_launch(void* const* d_in, const int* in_sizes, int n_in,
                              void* d_out, int out_size, void* d_ws, size_t ws_size,
                              hipStream_t stream) {
    const float* voxel = (const float*)d_in[0];   // [1,32,S]
    // d_in[1] = labels (unused)
    const float* label = (const float*)d_in[2];   // [105,32]
    const int* sidx    = (const int*)d_in[3];     // [K]
    const int* scls    = (const int*)d_in[4];     // [K]
    const int* negc    = (const int*)d_in[5];     // [K,8]

    int K = in_sizes[3];
    int S = in_sizes[1];                          // B*H*W*Z (B=1)

    float* partial = (float*)d_ws;
    float* out     = (float*)d_out;

    int total = K * NUM_NEG;
    int nb = (total + 255) / 256;                 // 210 blocks for K=6720
    lorentz_pair_kernel<<<nb, 256, 0, stream>>>(voxel, label, sidx, scls, negc,
                                                partial, K, S);
    lorentz_reduce_kernel<<<1, 64, 0, stream>>>(partial, nb, out,
                                                1.0f / (float)(K * NUM_NEG));
}

// Round 3
// 11.304 us; speedup vs baseline: 1.4025x; 1.0866x over previous
//
#include <hip/hip_runtime.h>
#include <math.h>

// LorentzRankingLoss, single-dispatch fused version.
// One thread per (anchor, negative) pair; per-block partials are published
// into 64-bit atomic slots (flag<<32 | float bits) in d_ws; block 0's first
// wave consumes all slots (spin-atomicExch to 0) and writes the final mean.
// Slots self-reset to 0 -> deterministic and poison-proof across graph replays.

#define NUM_NEG 8

__device__ __forceinline__ float lorentz_dist_row(const float x[32], float xt,
                                                  const float* __restrict__ yrow) {
    float yy = 0.f, dot = 0.f;
#pragma unroll
    for (int q = 0; q < 8; ++q) {
        float4 y4 = reinterpret_cast<const float4*>(yrow)[q];
        yy  = fmaf(y4.x, y4.x, yy);
        yy  = fmaf(y4.y, y4.y, yy);
        yy  = fmaf(y4.z, y4.z, yy);
        yy  = fmaf(y4.w, y4.w, yy);
        dot = fmaf(y4.x, x[q * 4 + 0], dot);
        dot = fmaf(y4.y, x[q * 4 + 1], dot);
        dot = fmaf(y4.z, x[q * 4 + 2], dot);
        dot = fmaf(y4.w, x[q * 4 + 3], dot);
    }
    float yt  = sqrtf(1.0f + yy);
    float arg = fmaxf(fmaf(xt, yt, -dot), 1.0f + 1e-7f);
    return acoshf(arg);
}

__global__ __launch_bounds__(256)
void lorentz_fused_kernel(const float* __restrict__ voxel,   // [32][S]
                          const float* __restrict__ label,   // [C][32]
                          const int* __restrict__ sidx,      // [K]
                          const int* __restrict__ scls,      // [K]
                          const int* __restrict__ negc,      // [K][8]
                          unsigned long long* __restrict__ slots, // [nb]
                          float* __restrict__ out,
                          int K, int S, int nb, float scale) {
    int t = blockIdx.x * 256 + threadIdx.x;
    float tri = 0.f;
    if (t < K * NUM_NEG) {
        int a = t >> 3;               // anchor; 8 sibling lanes share addresses
        int idx = sidx[a];
        float x[32];
#pragma unroll
        for (int d = 0; d < 32; ++d)
            x[d] = voxel[(size_t)d * (size_t)S + (size_t)idx];

        float xx = 0.f;
#pragma unroll
        for (int d = 0; d < 32; ++d) xx = fmaf(x[d], x[d], xx);
        float xt = sqrtf(1.0f + xx);

        float dpos = lorentz_dist_row(x, xt, label + (size_t)scls[a] * 32);
        float dneg = lorentz_dist_row(x, xt, label + (size_t)negc[t] * 32);
        tri = fmaxf(0.1f + dpos - dneg, 0.f);
    }

    // wave reduce (64 lanes) then cross-wave via LDS
#pragma unroll
    for (int o = 32; o > 0; o >>= 1) tri += __shfl_down(tri, o);

    __shared__ float ws4[4];
    int lane = threadIdx.x & 63, w = threadIdx.x >> 6;
    if (lane == 0) ws4[w] = tri;
    __syncthreads();

    // publish this block's partial: flag(1) and value share one atomic word
    if (threadIdx.x == 0) {
        float p = ws4[0] + ws4[1] + ws4[2] + ws4[3];
        unsigned long long payload =
            (1ULL << 32) | (unsigned long long)__float_as_uint(p);
        atomicExch(&slots[blockIdx.x], payload);
    }

    // block 0, wave 0: consume all slots (parallel spin), fixed-order sum
    if (blockIdx.x == 0 && threadIdx.x < 64) {
        float s = 0.f;
        for (int i = threadIdx.x; i < nb; i += 64) {
            unsigned long long v;
            do {
                v = atomicExch(&slots[i], 0ULL);   // consume + reset to 0
            } while ((v >> 32) != 1ULL);
            s += __uint_as_float((unsigned)(v & 0xffffffffULL));
        }
#pragma unroll
        for (int o = 32; o > 0; o >>= 1) s += __shfl_down(s, o);
        if (threadIdx.x == 0) out[0] = s * scale;
    }
}

extern "C" void kernel_launch(void* const* d_in, const int* in_sizes, int n_in,
                              void* d_out, int out_size, void* d_ws, size_t ws_size,
                              hipStream_t stream) {
    const float* voxel = (const float*)d_in[0];   // [1,32,S]
    // d_in[1] = labels (unused)
    const float* label = (const float*)d_in[2];   // [105,32]
    const int* sidx    = (const int*)d_in[3];     // [K]
    const int* scls    = (const int*)d_in[4];     // [K]
    const int* negc    = (const int*)d_in[5];     // [K,8]

    int K = in_sizes[3];
    int S = in_sizes[1];                          // B*H*W*Z (B=1)

    unsigned long long* slots = (unsigned long long*)d_ws;
    float* out = (float*)d_out;

    int total = K * NUM_NEG;
    int nb = (total + 255) / 256;                 // 210 blocks for K=6720
    lorentz_fused_kernel<<<nb, 256, 0, stream>>>(voxel, label, sidx, scls, negc,
                                                 slots, out, K, S, nb,
                                                 1.0f / (float)total);
}